// Round 9
// baseline (65.282 us; speedup 1.0000x reference)
//
#include <hip/hip_runtime.h>
#include <hip/hip_bf16.h>
#include <math.h>

#define BB 4
#define CC 256
#define NN 4096   // H*W
#define EE 32     // embedding channels

typedef __attribute__((ext_vector_type(8))) short bf16x8;    // 8 bf16 = 4 VGPR
typedef __attribute__((ext_vector_type(4))) float f32x4;
typedef __attribute__((ext_vector_type(16))) float f32x16;
typedef __attribute__((ext_vector_type(2))) unsigned uint32x2_t;

__device__ inline unsigned short f2bf(float x) {
    union { __hip_bfloat16 h; unsigned short u; } cv;
    cv.h = __float2bfloat16(x);
    return cv.u;
}
__device__ inline unsigned pk2(float lo, float hi) {
    return ((unsigned)f2bf(hi) << 16) | (unsigned)f2bf(lo);
}
__device__ inline float fexp2(float x) { return __builtin_amdgcn_exp2f(x); }
__device__ inline unsigned cvtpk(float lo, float hi) {
    unsigned r;
    asm("v_cvt_pk_bf16_f32 %0, %1, %2" : "=v"(r) : "v"(lo), "v"(hi));
    return r;
}
__device__ inline float bflo(unsigned u) {
    union { unsigned v; float f; } c; c.v = u << 16; return c.f;
}
__device__ inline float bfhi(unsigned u) {
    union { unsigned v; float f; } c; c.v = u & 0xFFFF0000u; return c.f;
}

// ---------------------------------------------------------------------------
// K0: one-time weight convert. wB rows 0-31 = kw, 32-63 = qw*log2e, 64-95 = vw.
// ---------------------------------------------------------------------------
__global__ __launch_bounds__(256) void wcvt_kernel(
    const float* __restrict__ kw, const float* __restrict__ kb,
    const float* __restrict__ qw, const float* __restrict__ qb,
    const float* __restrict__ vw, const float* __restrict__ vb,
    __hip_bfloat16* __restrict__ wB, float* __restrict__ bB)
{
    int r = blockIdx.x;            // 0..95
    int t = threadIdx.x;
    int rr = r & 31;
    const float* src; float scale = 1.f;
    if (r < 32)      src = kw;
    else if (r < 64) { src = qw; scale = 1.44269504f; }
    else             src = vw;
    if (t < 64) {
        float4 v = *(const float4*)(src + rr * 256 + t * 4);
        uint2 p;
        p.x = pk2(v.x * scale, v.y * scale);
        p.y = pk2(v.z * scale, v.w * scale);
        *(uint2*)((unsigned short*)wB + r * 256 + t * 4) = p;
    }
    if (r == 0 && t >= 64 && t < 160) {
        int e = t - 64;
        const float* bs = (e < 32) ? kb : ((e < 64) ? qb : vb);
        float sc = (e >= 32 && e < 64) ? 1.44269504f : 1.f;
        bB[e] = bs[e & 31] * sc;
    }
}

// ---------------------------------------------------------------------------
// K1: MFMA QKV projection (x read once, all 96 channels).
//   fT/gT: [B][N][32]   hT: [B][32][N]
// grid = B*(N/32) = 512, block = 256.
// ---------------------------------------------------------------------------
__global__ __launch_bounds__(256) void proj_kernel(
    const float* __restrict__ x,
    const __hip_bfloat16* __restrict__ wB, const float* __restrict__ bB,
    __hip_bfloat16* __restrict__ fT, __hip_bfloat16* __restrict__ gT,
    __hip_bfloat16* __restrict__ hT)
{
    __shared__ unsigned xs[32][132];   // stride 132 u32: b128 reads conflict-free
    int b     = blockIdx.x >> 7;
    int ibase = (blockIdx.x & 127) << 5;
    int wv    = threadIdx.x >> 6;
    int l     = threadIdx.x & 63;
    int il    = l & 31;
    int pg    = (wv << 1) | (l >> 5);   // 8 c-pair groups

    const float* xb = x + (size_t)b * CC * NN + ibase + il;
#pragma unroll
    for (int j = 0; j < 16; ++j) {
        int p = pg + (j << 3);          // c-pair 0..127
        float lo = xb[(size_t)(2 * p) * NN];
        float hi = xb[(size_t)(2 * p + 1) * NN];
        xs[il][p] = pk2(lo, hi);
    }
    __syncthreads();

    int q15  = l & 15, g = l >> 4;
    int isub = wv & 1, eh = wv >> 1;
    int irow = (isub << 4) + q15;
    const __hip_bfloat16* w0 = wB + ((size_t)(eh * 48) + q15) * 256;

    f32x4 a0 = {0,0,0,0}, a1 = {0,0,0,0}, a2 = {0,0,0,0};
#pragma unroll
    for (int kk = 0; kk < 8; ++kk) {
        bf16x8 Bf = *(const bf16x8*)&xs[irow][kk * 16 + 4 * g];
        int co = kk * 32 + 8 * g;
        bf16x8 A0 = *(const bf16x8*)(w0 + co);
        bf16x8 A1 = *(const bf16x8*)(w0 + 16 * 256 + co);
        bf16x8 A2 = *(const bf16x8*)(w0 + 32 * 256 + co);
        a0 = __builtin_amdgcn_mfma_f32_16x16x32_bf16(A0, Bf, a0, 0, 0, 0);
        a1 = __builtin_amdgcn_mfma_f32_16x16x32_bf16(A1, Bf, a1, 0, 0, 0);
        a2 = __builtin_amdgcn_mfma_f32_16x16x32_bf16(A2, Bf, a2, 0, 0, 0);
    }

    int ig = ibase + irow;
    auto emit = [&](f32x4 acc, int T) {
        float4 bb = *(const float4*)(bB + T * 16 + 4 * g);
        float d0 = acc[0] + bb.x, d1 = acc[1] + bb.y;
        float d2 = acc[2] + bb.z, d3 = acc[3] + bb.w;
        if (T < 4) {
            __hip_bfloat16* dst = (T < 2) ? fT : gT;
            int eoff = ((T & 1) << 4) + 4 * g;
            uint2 pq; pq.x = pk2(d0, d1); pq.y = pk2(d2, d3);
            *(uint2*)((unsigned short*)dst + ((size_t)b * NN + ig) * EE + eoff) = pq;
        } else {
            unsigned short* dst = (unsigned short*)hT;
            int e = ((T - 4) << 4) + 4 * g;
            size_t base = ((size_t)b * EE + e) * NN + ig;
            dst[base]          = f2bf(d0);
            dst[base + NN]     = f2bf(d1);
            dst[base + 2 * NN] = f2bf(d2);
            dst[base + 3 * NN] = f2bf(d3);
        }
    };
    emit(a0, eh * 3 + 0);
    emit(a1, eh * 3 + 1);
    emit(a2, eh * 3 + 2);
}

// ---------------------------------------------------------------------------
// K2: fused flash attention + output 1x1 conv + residual.
// 64 queries/block (halves L2 K/V traffic vs 32q), 16 waves = 2 qgroups x
// 8 key-splits; fixed m=0 softmax (logits bounded, see r7); per-wave inner
// loop identical to round 8.  Epilogue: bf16-packed LDS merge -> vbuf ->
// all 16 waves compute o = aw.v + ab, y = gamma*o + x (coalesced over i).
// grid = B*(N/64) = 256 (1 block/CU), block = 1024, 4 waves/EU.
// ---------------------------------------------------------------------------
__global__ __launch_bounds__(1024, 4) void attn_kernel(
    const __hip_bfloat16* __restrict__ fT,
    const __hip_bfloat16* __restrict__ gT,
    const __hip_bfloat16* __restrict__ hT,
    const float* __restrict__ aw, const float* __restrict__ ab,
    const float* __restrict__ x,  const float* __restrict__ gamma_p,
    float* __restrict__ y, float* __restrict__ o)
{
    int b     = blockIdx.x >> 6;
    int ibase = (blockIdx.x & 63) << 6;
    int wv    = threadIdx.x >> 6;    // 16 waves
    int lane  = threadIdx.x & 63;
    int qg    = wv >> 3;             // q-group 0/1
    int ks    = wv & 7;              // key-split 0..7
    int q     = lane & 31;
    int h     = lane >> 5;           // key-half
    int qbase = ibase + qg * 32;

    const __hip_bfloat16* fb = fT + (size_t)b * NN * EE;
    const __hip_bfloat16* gb = gT + (size_t)b * NN * EE;
    const __hip_bfloat16* hb = hT + (size_t)b * EE * NN + (size_t)q * NN; // e=q row

    bf16x8 Qf0 = *(const bf16x8*)(gb + (size_t)(qbase + q) * EE + 8 * h);
    bf16x8 Qf1 = *(const bf16x8*)(gb + (size_t)(qbase + q) * EE + 16 + 8 * h);

    float l = 0.f;
    f32x16 O = {0,0,0,0,0,0,0,0,0,0,0,0,0,0,0,0};
    const f32x16 z16 = {0,0,0,0,0,0,0,0,0,0,0,0,0,0,0,0};

    int k0 = ks * 512;
    bf16x8 K0 = *(const bf16x8*)(fb + (size_t)(k0 + q) * EE + 8 * h);
    bf16x8 K1 = *(const bf16x8*)(fb + (size_t)(k0 + q) * EE + 16 + 8 * h);
    bf16x8 V0 = *(const bf16x8*)(hb + k0 + 8 * h);
    bf16x8 V1 = *(const bf16x8*)(hb + k0 + 16 + 8 * h);

    for (int c = 0; c < 16; ++c) {
        int kn = (k0 + 32) & (NN - 1);   // clamp last prefetch into range
        bf16x8 nK0 = *(const bf16x8*)(fb + (size_t)(kn + q) * EE + 8 * h);
        bf16x8 nK1 = *(const bf16x8*)(fb + (size_t)(kn + q) * EE + 16 + 8 * h);
        bf16x8 nV0 = *(const bf16x8*)(hb + kn + 8 * h);
        bf16x8 nV1 = *(const bf16x8*)(hb + kn + 16 + 8 * h);

        __builtin_amdgcn_s_setprio(1);
        f32x16 S = __builtin_amdgcn_mfma_f32_32x32x16_bf16(K0, Qf0, z16, 0, 0, 0);
        S = __builtin_amdgcn_mfma_f32_32x32x16_bf16(K1, Qf1, S, 0, 0, 0);
        __builtin_amdgcn_s_setprio(0);

        float p[16];
#pragma unroll
        for (int r = 0; r < 16; ++r) p[r] = fexp2(S[r]);
        float s0 = (p[0] + p[1]) + (p[2] + p[3]);
        float s1 = (p[4] + p[5]) + (p[6] + p[7]);
        float s2 = (p[8] + p[9]) + (p[10] + p[11]);
        float s3 = (p[12] + p[13]) + (p[14] + p[15]);
        l += (s0 + s1) + (s2 + s3);

        unsigned j0 = cvtpk(p[0], p[1]),   j1 = cvtpk(p[2], p[3]);
        unsigned j2 = cvtpk(p[4], p[5]),   j3 = cvtpk(p[6], p[7]);
        unsigned j4 = cvtpk(p[8], p[9]),   j5 = cvtpk(p[10], p[11]);
        unsigned j6 = cvtpk(p[12], p[13]), j7 = cvtpk(p[14], p[15]);

        uint32x2_t sA = __builtin_amdgcn_permlane32_swap(j0, j2, false, false);
        uint32x2_t sB = __builtin_amdgcn_permlane32_swap(j1, j3, false, false);
        union { unsigned u[4]; bf16x8 v; } P1;
        P1.u[0] = sA.x; P1.u[1] = sB.x; P1.u[2] = sA.y; P1.u[3] = sB.y;
        uint32x2_t sC = __builtin_amdgcn_permlane32_swap(j4, j6, false, false);
        uint32x2_t sD = __builtin_amdgcn_permlane32_swap(j5, j7, false, false);
        union { unsigned u[4]; bf16x8 v; } P2;
        P2.u[0] = sC.x; P2.u[1] = sD.x; P2.u[2] = sC.y; P2.u[3] = sD.y;

        __builtin_amdgcn_s_setprio(1);
        O = __builtin_amdgcn_mfma_f32_32x32x16_bf16(V0, P1.v, O, 0, 0, 0);
        O = __builtin_amdgcn_mfma_f32_32x32x16_bf16(V1, P2.v, O, 0, 0, 0);
        __builtin_amdgcn_s_setprio(0);

        K0 = nK0; K1 = nK1; V0 = nV0; V1 = nV1;
        k0 = kn;
    }

    // ---- merge 8 key-splits per q-group (pure sums, bf16-packed LDS) ----
    __shared__ unsigned sOp[16][64][9];   // 8 u32 (16 bf16) + pad
    __shared__ float    slx[16][64];
    __shared__ float    vbuf[64][33];     // merged v, stride 33: 2-way banks
    slx[wv][lane] = l;
#pragma unroll
    for (int r = 0; r < 8; ++r) sOp[wv][lane][r] = cvtpk(O[2*r], O[2*r+1]);
    __syncthreads();

    if (ks == 0) {                        // waves 0 and 8 merge their q-group
        float L = 0.f;
        float Of[16];
#pragma unroll
        for (int r = 0; r < 16; ++r) Of[r] = 0.f;
#pragma unroll
        for (int w = 0; w < 8; ++w) {
            L += slx[wv + w][lane];
#pragma unroll
            for (int r = 0; r < 8; ++r) {
                unsigned u = sOp[wv + w][lane][r];
                Of[2*r]   += bflo(u);
                Of[2*r+1] += bfhi(u);
            }
        }
        L += __shfl_xor(L, 32, 64);       // halves hold disjoint keys
        float inv = 1.f / L;
        int pos = qg * 32 + q;
#pragma unroll
        for (int gi = 0; gi < 4; ++gi)
#pragma unroll
            for (int r = 0; r < 4; ++r)
                vbuf[pos][8 * gi + 4 * h + r] = Of[4 * gi + r] * inv;
    }
    __syncthreads();

    // ---- fused output 1x1 conv + residual ----
    int pos = threadIdx.x & 63;
    int cog = threadIdx.x >> 6;           // = wv; 16 co-groups
    float gm = gamma_p[0];
    float vv[EE];
#pragma unroll
    for (int e = 0; e < EE; ++e) vv[e] = vbuf[pos][e];
    int i = ibase + pos;
#pragma unroll
    for (int j = 0; j < 16; ++j) {
        int co = cog * 16 + j;
        float s = ab[co];
#pragma unroll
        for (int e = 0; e < EE; ++e)
            s = fmaf(aw[co * EE + e], vv[e], s);   // aw uniform -> scalar loads
        size_t idx = ((size_t)b * CC + co) * NN + i;
        o[idx] = s;
        y[idx] = fmaf(gm, s, x[idx]);
    }
}

// ---------------------------------------------------------------------------
extern "C" void kernel_launch(void* const* d_in, const int* in_sizes, int n_in,
                              void* d_out, int out_size, void* d_ws, size_t ws_size,
                              hipStream_t stream)
{
    const float* x  = (const float*)d_in[0];
    const float* kw = (const float*)d_in[1];
    const float* kb = (const float*)d_in[2];
    const float* qw = (const float*)d_in[3];
    const float* qb = (const float*)d_in[4];
    const float* vw = (const float*)d_in[5];
    const float* vb = (const float*)d_in[6];
    const float* aw = (const float*)d_in[7];
    const float* ab = (const float*)d_in[8];
    const float* gm = (const float*)d_in[9];

    float* y = (float*)d_out;
    float* o = y + (size_t)BB * CC * NN;

    // ws: bB f32 [128] | wB bf16 [96][256] | fT,gT bf16 [B][N][32] | hT bf16 [B][32][N]
    float*          bB = (float*)d_ws;
    __hip_bfloat16* wB = (__hip_bfloat16*)(bB + 128);
    __hip_bfloat16* fT = wB + 96 * 256;
    __hip_bfloat16* gT = fT + (size_t)BB * NN * EE;
    __hip_bfloat16* hT = gT + (size_t)BB * NN * EE;

    wcvt_kernel<<<96, 256, 0, stream>>>(kw, kb, qw, qb, vw, vb, wB, bB);
    proj_kernel<<<BB * (NN / 32), 256, 0, stream>>>(x, wB, bB, fT, gT, hT);
    attn_kernel<<<BB * (NN / 64), 1024, 0, stream>>>(
        fT, gT, hT, aw, ab, x, gm, y, o);
}

// Round 10
// 62.132 us; speedup vs baseline: 1.0507x; 1.0507x over previous
//
#include <hip/hip_runtime.h>
#include <hip/hip_bf16.h>
#include <math.h>

#define BB 4
#define CC 256
#define NN 4096   // H*W
#define EE 32     // embedding channels

typedef __attribute__((ext_vector_type(8))) short bf16x8;    // 8 bf16 = 4 VGPR
typedef __attribute__((ext_vector_type(4))) float f32x4;
typedef __attribute__((ext_vector_type(16))) float f32x16;
typedef __attribute__((ext_vector_type(2))) unsigned uint32x2_t;

__device__ inline unsigned short f2bf(float x) {
    union { __hip_bfloat16 h; unsigned short u; } cv;
    cv.h = __float2bfloat16(x);
    return cv.u;
}
__device__ inline unsigned pk2(float lo, float hi) {
    return ((unsigned)f2bf(hi) << 16) | (unsigned)f2bf(lo);
}
__device__ inline float fexp2(float x) { return __builtin_amdgcn_exp2f(x); }
__device__ inline unsigned cvtpk(float lo, float hi) {
    unsigned r;
    asm("v_cvt_pk_bf16_f32 %0, %1, %2" : "=v"(r) : "v"(lo), "v"(hi));
    return r;
}
__device__ inline float bflo(unsigned u) {
    union { unsigned v; float f; } c; c.v = u << 16; return c.f;
}
__device__ inline float bfhi(unsigned u) {
    union { unsigned v; float f; } c; c.v = u & 0xFFFF0000u; return c.f;
}

// ---------------------------------------------------------------------------
// K0: one-time weight convert. wB rows 0-31 = kw, 32-63 = qw*log2e, 64-95 = vw.
// ---------------------------------------------------------------------------
__global__ __launch_bounds__(256) void wcvt_kernel(
    const float* __restrict__ kw, const float* __restrict__ kb,
    const float* __restrict__ qw, const float* __restrict__ qb,
    const float* __restrict__ vw, const float* __restrict__ vb,
    __hip_bfloat16* __restrict__ wB, float* __restrict__ bB)
{
    int r = blockIdx.x;            // 0..95
    int t = threadIdx.x;
    int rr = r & 31;
    const float* src; float scale = 1.f;
    if (r < 32)      src = kw;
    else if (r < 64) { src = qw; scale = 1.44269504f; }
    else             src = vw;
    if (t < 64) {
        float4 v = *(const float4*)(src + rr * 256 + t * 4);
        uint2 p;
        p.x = pk2(v.x * scale, v.y * scale);
        p.y = pk2(v.z * scale, v.w * scale);
        *(uint2*)((unsigned short*)wB + r * 256 + t * 4) = p;
    }
    if (r == 0 && t >= 64 && t < 160) {
        int e = t - 64;
        const float* bs = (e < 32) ? kb : ((e < 64) ? qb : vb);
        float sc = (e >= 32 && e < 64) ? 1.44269504f : 1.f;
        bB[e] = bs[e & 31] * sc;
    }
}

// ---------------------------------------------------------------------------
// K1: MFMA QKV projection (x read once, all 96 channels).
//   fT/gT: [B][N][32]   hT: TILED [B][N/32][32e][32k] (2KB per key-tile so
//   attention's V A-frag reads are a dense 2KB region, not a 256KB scatter)
// grid = B*(N/32) = 512, block = 256.
// ---------------------------------------------------------------------------
__global__ __launch_bounds__(256) void proj_kernel(
    const float* __restrict__ x,
    const __hip_bfloat16* __restrict__ wB, const float* __restrict__ bB,
    __hip_bfloat16* __restrict__ fT, __hip_bfloat16* __restrict__ gT,
    __hip_bfloat16* __restrict__ hT)
{
    __shared__ unsigned xs[32][132];   // stride 132 u32: b128 reads conflict-free
    int b     = blockIdx.x >> 7;
    int ibase = (blockIdx.x & 127) << 5;
    int wv    = threadIdx.x >> 6;
    int l     = threadIdx.x & 63;
    int il    = l & 31;
    int pg    = (wv << 1) | (l >> 5);   // 8 c-pair groups

    const float* xb = x + (size_t)b * CC * NN + ibase + il;
#pragma unroll
    for (int j = 0; j < 16; ++j) {
        int p = pg + (j << 3);          // c-pair 0..127
        float lo = xb[(size_t)(2 * p) * NN];
        float hi = xb[(size_t)(2 * p + 1) * NN];
        xs[il][p] = pk2(lo, hi);
    }
    __syncthreads();

    int q15  = l & 15, g = l >> 4;
    int isub = wv & 1, eh = wv >> 1;
    int irow = (isub << 4) + q15;
    const __hip_bfloat16* w0 = wB + ((size_t)(eh * 48) + q15) * 256;

    f32x4 a0 = {0,0,0,0}, a1 = {0,0,0,0}, a2 = {0,0,0,0};
#pragma unroll
    for (int kk = 0; kk < 8; ++kk) {
        bf16x8 Bf = *(const bf16x8*)&xs[irow][kk * 16 + 4 * g];
        int co = kk * 32 + 8 * g;
        bf16x8 A0 = *(const bf16x8*)(w0 + co);
        bf16x8 A1 = *(const bf16x8*)(w0 + 16 * 256 + co);
        bf16x8 A2 = *(const bf16x8*)(w0 + 32 * 256 + co);
        a0 = __builtin_amdgcn_mfma_f32_16x16x32_bf16(A0, Bf, a0, 0, 0, 0);
        a1 = __builtin_amdgcn_mfma_f32_16x16x32_bf16(A1, Bf, a1, 0, 0, 0);
        a2 = __builtin_amdgcn_mfma_f32_16x16x32_bf16(A2, Bf, a2, 0, 0, 0);
    }

    int ig = ibase + irow;
    auto emit = [&](f32x4 acc, int T) {
        float4 bb = *(const float4*)(bB + T * 16 + 4 * g);
        float d0 = acc[0] + bb.x, d1 = acc[1] + bb.y;
        float d2 = acc[2] + bb.z, d3 = acc[3] + bb.w;
        if (T < 4) {
            __hip_bfloat16* dst = (T < 2) ? fT : gT;
            int eoff = ((T & 1) << 4) + 4 * g;
            uint2 pq; pq.x = pk2(d0, d1); pq.y = pk2(d2, d3);
            *(uint2*)((unsigned short*)dst + ((size_t)b * NN + ig) * EE + eoff) = pq;
        } else {
            unsigned short* dst = (unsigned short*)hT;
            int e  = ((T - 4) << 4) + 4 * g;
            int kt = ig >> 5, kk2 = ig & 31;
            size_t base = ((size_t)(b * 128 + kt) * 32 + e) * 32 + kk2;
            dst[base]       = f2bf(d0);
            dst[base + 32]  = f2bf(d1);
            dst[base + 64]  = f2bf(d2);
            dst[base + 96]  = f2bf(d3);
        }
    };
    emit(a0, eh * 3 + 0);
    emit(a1, eh * 3 + 1);
    emit(a2, eh * 3 + 2);
}

// ---------------------------------------------------------------------------
// K2: MFMA flash attention, 64 QUERIES PER WAVE (q-sets A/B share every K/V
// register load -> L2 bytes per query halved vs r8/r9), fixed m=0 softmax,
// tiled-V loads (dense 2KB regions). 16 key-splits x 256 keys, 8 chunks.
// lane (q=lane&31, h=lane>>5): S[r] = score(key (r&3)+8*(r>>2)+4h, q).
// P redistribution: (u0,u2)=swap(j0,j2), (u1,u3)=swap(j1,j3); keys16-31:
// swap(j4,j6),(j5,j7). 16 waves merge via LDS (pure sums).
// vT out: [B][N][32] f32. grid = B*(N/64) = 256, block = 1024, 4 waves/EU.
// ---------------------------------------------------------------------------
__global__ __launch_bounds__(1024, 4) void attn_kernel(
    const __hip_bfloat16* __restrict__ fT,
    const __hip_bfloat16* __restrict__ gT,
    const __hip_bfloat16* __restrict__ hT,
    float* __restrict__ vT)
{
    int b     = blockIdx.x >> 6;
    int ibase = (blockIdx.x & 63) << 6;
    int wv    = threadIdx.x >> 6;    // key-split 0..15
    int lane  = threadIdx.x & 63;
    int q     = lane & 31;
    int h     = lane >> 5;           // key-half

    const __hip_bfloat16* fb = fT + (size_t)b * NN * EE;
    const __hip_bfloat16* gb = gT + (size_t)b * NN * EE;
    const __hip_bfloat16* hb = hT + (size_t)b * NN * EE + q * 32 + 8 * h; // e=q

    bf16x8 Qa0 = *(const bf16x8*)(gb + (size_t)(ibase + q) * EE + 8 * h);
    bf16x8 Qa1 = *(const bf16x8*)(gb + (size_t)(ibase + q) * EE + 16 + 8 * h);
    bf16x8 Qb0 = *(const bf16x8*)(gb + (size_t)(ibase + 32 + q) * EE + 8 * h);
    bf16x8 Qb1 = *(const bf16x8*)(gb + (size_t)(ibase + 32 + q) * EE + 16 + 8 * h);

    float lA = 0.f, lB = 0.f;
    f32x16 OA = {0,0,0,0,0,0,0,0,0,0,0,0,0,0,0,0};
    f32x16 OB = {0,0,0,0,0,0,0,0,0,0,0,0,0,0,0,0};
    const f32x16 z16 = {0,0,0,0,0,0,0,0,0,0,0,0,0,0,0,0};

    int k0 = wv * 256;
    bf16x8 K0 = *(const bf16x8*)(fb + (size_t)(k0 + q) * EE + 8 * h);
    bf16x8 K1 = *(const bf16x8*)(fb + (size_t)(k0 + q) * EE + 16 + 8 * h);

    for (int c = 0; c < 8; ++c) {
        int kn = (k0 + 32) & (NN - 1);   // last prefetch clamped into range
        bf16x8 nK0 = *(const bf16x8*)(fb + (size_t)(kn + q) * EE + 8 * h);
        bf16x8 nK1 = *(const bf16x8*)(fb + (size_t)(kn + q) * EE + 16 + 8 * h);
        bf16x8 V0  = *(const bf16x8*)(hb + (size_t)k0 * 32);       // tiled V
        bf16x8 V1  = *(const bf16x8*)(hb + (size_t)k0 * 32 + 16);

        __builtin_amdgcn_s_setprio(1);
        f32x16 SA = __builtin_amdgcn_mfma_f32_32x32x16_bf16(K0, Qa0, z16, 0, 0, 0);
        SA = __builtin_amdgcn_mfma_f32_32x32x16_bf16(K1, Qa1, SA, 0, 0, 0);
        __builtin_amdgcn_s_setprio(0);

        {   // ---- q-set A softmax + PV ----
            float p[16];
#pragma unroll
            for (int r = 0; r < 16; ++r) p[r] = fexp2(SA[r]);
            lA += ((p[0]+p[1])+(p[2]+p[3])) + ((p[4]+p[5])+(p[6]+p[7]))
                + ((p[8]+p[9])+(p[10]+p[11])) + ((p[12]+p[13])+(p[14]+p[15]));
            unsigned j0 = cvtpk(p[0], p[1]),   j1 = cvtpk(p[2], p[3]);
            unsigned j2 = cvtpk(p[4], p[5]),   j3 = cvtpk(p[6], p[7]);
            unsigned j4 = cvtpk(p[8], p[9]),   j5 = cvtpk(p[10], p[11]);
            unsigned j6 = cvtpk(p[12], p[13]), j7 = cvtpk(p[14], p[15]);
            uint32x2_t sA2 = __builtin_amdgcn_permlane32_swap(j0, j2, false, false);
            uint32x2_t sB2 = __builtin_amdgcn_permlane32_swap(j1, j3, false, false);
            union { unsigned u[4]; bf16x8 v; } P1;
            P1.u[0] = sA2.x; P1.u[1] = sB2.x; P1.u[2] = sA2.y; P1.u[3] = sB2.y;
            uint32x2_t sC2 = __builtin_amdgcn_permlane32_swap(j4, j6, false, false);
            uint32x2_t sD2 = __builtin_amdgcn_permlane32_swap(j5, j7, false, false);
            union { unsigned u[4]; bf16x8 v; } P2;
            P2.u[0] = sC2.x; P2.u[1] = sD2.x; P2.u[2] = sC2.y; P2.u[3] = sD2.y;
            __builtin_amdgcn_s_setprio(1);
            OA = __builtin_amdgcn_mfma_f32_32x32x16_bf16(V0, P1.v, OA, 0, 0, 0);
            OA = __builtin_amdgcn_mfma_f32_32x32x16_bf16(V1, P2.v, OA, 0, 0, 0);
            __builtin_amdgcn_s_setprio(0);
        }

        __builtin_amdgcn_s_setprio(1);
        f32x16 SB = __builtin_amdgcn_mfma_f32_32x32x16_bf16(K0, Qb0, z16, 0, 0, 0);
        SB = __builtin_amdgcn_mfma_f32_32x32x16_bf16(K1, Qb1, SB, 0, 0, 0);
        __builtin_amdgcn_s_setprio(0);

        {   // ---- q-set B softmax + PV ----
            float p[16];
#pragma unroll
            for (int r = 0; r < 16; ++r) p[r] = fexp2(SB[r]);
            lB += ((p[0]+p[1])+(p[2]+p[3])) + ((p[4]+p[5])+(p[6]+p[7]))
                + ((p[8]+p[9])+(p[10]+p[11])) + ((p[12]+p[13])+(p[14]+p[15]));
            unsigned j0 = cvtpk(p[0], p[1]),   j1 = cvtpk(p[2], p[3]);
            unsigned j2 = cvtpk(p[4], p[5]),   j3 = cvtpk(p[6], p[7]);
            unsigned j4 = cvtpk(p[8], p[9]),   j5 = cvtpk(p[10], p[11]);
            unsigned j6 = cvtpk(p[12], p[13]), j7 = cvtpk(p[14], p[15]);
            uint32x2_t sA2 = __builtin_amdgcn_permlane32_swap(j0, j2, false, false);
            uint32x2_t sB2 = __builtin_amdgcn_permlane32_swap(j1, j3, false, false);
            union { unsigned u[4]; bf16x8 v; } P1;
            P1.u[0] = sA2.x; P1.u[1] = sB2.x; P1.u[2] = sA2.y; P1.u[3] = sB2.y;
            uint32x2_t sC2 = __builtin_amdgcn_permlane32_swap(j4, j6, false, false);
            uint32x2_t sD2 = __builtin_amdgcn_permlane32_swap(j5, j7, false, false);
            union { unsigned u[4]; bf16x8 v; } P2;
            P2.u[0] = sC2.x; P2.u[1] = sD2.x; P2.u[2] = sC2.y; P2.u[3] = sD2.y;
            __builtin_amdgcn_s_setprio(1);
            OB = __builtin_amdgcn_mfma_f32_32x32x16_bf16(V0, P1.v, OB, 0, 0, 0);
            OB = __builtin_amdgcn_mfma_f32_32x32x16_bf16(V1, P2.v, OB, 0, 0, 0);
            __builtin_amdgcn_s_setprio(0);
        }

        K0 = nK0; K1 = nK1;
        k0 = kn;
    }

    // ---- merge 16 key-splits (pure sums, bf16-packed LDS) ----
    __shared__ unsigned sOp[16][64][17];   // 16 u32 (A:8, B:8) + pad
    __shared__ float    slx[16][64][2];
    slx[wv][lane][0] = lA;
    slx[wv][lane][1] = lB;
#pragma unroll
    for (int r = 0; r < 8; ++r) {
        sOp[wv][lane][r]     = cvtpk(OA[2*r], OA[2*r+1]);
        sOp[wv][lane][8 + r] = cvtpk(OB[2*r], OB[2*r+1]);
    }
    __syncthreads();

    if (wv < 2) {                          // wave0 -> set A, wave1 -> set B
        int set = wv;
        float L = 0.f;
        float Of[16];
#pragma unroll
        for (int r = 0; r < 16; ++r) Of[r] = 0.f;
#pragma unroll
        for (int w = 0; w < 16; ++w) {
            L += slx[w][lane][set];
#pragma unroll
            for (int r = 0; r < 8; ++r) {
                unsigned u = sOp[w][lane][set * 8 + r];
                Of[2*r]   += bflo(u);
                Of[2*r+1] += bfhi(u);
            }
        }
        L += __shfl_xor(L, 32, 64);        // halves hold disjoint keys
        float inv = 1.f / L;
        float* vp = vT + ((size_t)b * NN + ibase + set * 32 + q) * EE;
#pragma unroll
        for (int gi = 0; gi < 4; ++gi) {
            f32x4 ov;
#pragma unroll
            for (int r = 0; r < 4; ++r) ov[r] = Of[4 * gi + r] * inv;
            *(f32x4*)(vp + 8 * gi + 4 * h) = ov;   // e = 8*gi + 4h + 0..3
        }
    }
}

// ---------------------------------------------------------------------------
// K3: output 1x1 conv + residual. vT is [B][N][32] f32 (contiguous per i).
// grid = B * 16 * 16 = 1024, block = 256 (16 co per thread).
// ---------------------------------------------------------------------------
__global__ __launch_bounds__(256) void out_kernel(
    const float* __restrict__ vT, const float* __restrict__ aw,
    const float* __restrict__ ab, const float* __restrict__ x,
    const float* __restrict__ gamma_p,
    float* __restrict__ y, float* __restrict__ o)
{
    int blk    = blockIdx.x;
    int csplit = blk & 15;
    int itile  = (blk >> 4) & 15;
    int b      = blk >> 8;
    int i      = itile * 256 + threadIdx.x;
    float gm   = gamma_p[0];

    const float4* vp4 = (const float4*)(vT + ((size_t)b * NN + i) * EE);
    float vr[EE];
#pragma unroll
    for (int u = 0; u < 8; ++u) {
        float4 t = vp4[u];
        vr[4*u+0] = t.x; vr[4*u+1] = t.y; vr[4*u+2] = t.z; vr[4*u+3] = t.w;
    }

    int co0 = csplit * 16;
#pragma unroll
    for (int co = co0; co < co0 + 16; ++co) {
        float s = ab[co];
#pragma unroll
        for (int e = 0; e < EE; ++e)
            s = fmaf(aw[co * EE + e], vr[e], s);
        size_t idx = ((size_t)b * CC + co) * NN + i;
        o[idx] = s;
        y[idx] = fmaf(gm, s, x[idx]);
    }
}

// ---------------------------------------------------------------------------
extern "C" void kernel_launch(void* const* d_in, const int* in_sizes, int n_in,
                              void* d_out, int out_size, void* d_ws, size_t ws_size,
                              hipStream_t stream)
{
    const float* x  = (const float*)d_in[0];
    const float* kw = (const float*)d_in[1];
    const float* kb = (const float*)d_in[2];
    const float* qw = (const float*)d_in[3];
    const float* qb = (const float*)d_in[4];
    const float* vw = (const float*)d_in[5];
    const float* vb = (const float*)d_in[6];
    const float* aw = (const float*)d_in[7];
    const float* ab = (const float*)d_in[8];
    const float* gm = (const float*)d_in[9];

    float* y = (float*)d_out;
    float* o = y + (size_t)BB * CC * NN;

    // ws: vT f32 [B][N][32] | bB f32 [128] | wB bf16 [96][256] | fT,gT bf16
    // [B][N][32] | hT bf16 tiled [B][N/32][32][32]
    float*          vT = (float*)d_ws;
    float*          bB = vT + (size_t)BB * NN * EE;
    __hip_bfloat16* wB = (__hip_bfloat16*)(bB + 128);
    __hip_bfloat16* fT = wB + 96 * 256;
    __hip_bfloat16* gT = fT + (size_t)BB * NN * EE;
    __hip_bfloat16* hT = gT + (size_t)BB * NN * EE;

    wcvt_kernel<<<96, 256, 0, stream>>>(kw, kb, qw, qb, vw, vb, wB, bB);
    proj_kernel<<<BB * (NN / 32), 256, 0, stream>>>(x, wB, bB, fT, gT, hT);
    attn_kernel<<<BB * (NN / 64), 1024, 0, stream>>>(fT, gT, hT, vT);
    out_kernel<<<BB * 16 * 16, 256, 0, stream>>>(vT, aw, ab, x, gm, y, o);
}